// Round 5
// baseline (210.327 us; speedup 1.0000x reference)
//
#include <hip/hip_runtime.h>
#include <math.h>

#define NB 8
#define NN 16384
#define NT 8
#define ND 256
#define NEG_FILL_F (-1e20f)

// monotonic float->uint key: order(key) == order(float), ascending
__device__ __forceinline__ unsigned fkey(float s){
  unsigned u = __float_as_uint(s);
  return (u & 0x80000000u) ? ~u : (u | 0x80000000u);
}
__device__ __forceinline__ float fkey_inv(unsigned k){
  unsigned u = (k & 0x80000000u) ? (k ^ 0x80000000u) : ~k;
  return __uint_as_float(u);
}

__device__ __forceinline__ float prob_of(const float4 x, const float4 y){
  float m = fmaxf(fmaxf(fmaxf(x.x,x.y),fmaxf(x.z,x.w)),
                  fmaxf(fmaxf(y.x,y.y),fmaxf(y.z,y.w)));
  float e0=expf(x.x-m), e1=expf(x.y-m), e2=expf(x.z-m), e3=expf(x.w-m);
  float e4=expf(y.x-m), e5=expf(y.y-m), e6=expf(y.z-m), e7=expf(y.w-m);
  float sum = ((((((e0+e1)+e2)+e3)+e4)+e5)+e6)+e7;
  float pm = fmaxf(fmaxf(fmaxf(e1,e2),fmaxf(e3,e4)),fmaxf(fmaxf(e5,e6),e7));
  return pm/sum;   // max_{t>=1} softmax[t] == max_{t>=1} e_t / sum (division monotone)
}

// keys[b,n] = fkey( span_mask ? max(prob_a, prob_b) : NEG_FILL )
// writes this block's high-byte histogram to its private gpart slot (no atomics, no init)
__global__ void k_scores(const float* __restrict__ sa, const float* __restrict__ sb,
                         const int* __restrict__ mask, unsigned* __restrict__ outk,
                         int* __restrict__ gpart){
  __shared__ int lh[256];
  const int t = threadIdx.x;
  lh[t] = 0;
  __syncthreads();
  int i = blockIdx.x*256 + t;            // 256 threads/block, 64 blocks per batch
  const float4* pa = (const float4*)(sa + (size_t)i*NT);
  const float4* pb = (const float4*)(sb + (size_t)i*NT);
  float4 a0=pa[0], a1=pa[1], b0=pb[0], b1=pb[1];
  float p = fmaxf(prob_of(a0,a1), prob_of(b0,b1));
  unsigned k = fkey(mask[i] ? p : NEG_FILL_F);
  outk[i] = k;
  atomicAdd(&lh[k>>24], 1);
  __syncthreads();
  gpart[blockIdx.x*256 + t] = lh[t];     // full 256-bin partial, plain store
}

// exclusive scan over 512 threads (thread order == span order), 8 waves
__device__ __forceinline__ int block_scan_excl512(int v, int* lds, int tid){
  __syncthreads();   // protect lds reuse across calls
  int lane = tid & 63, wave = tid >> 6;
  int x = v;
  #pragma unroll
  for (int off=1; off<64; off<<=1){
    int y = __shfl_up(x, off, 64);
    if (lane >= off) x += y;
  }
  if (lane == 63) lds[wave] = x;
  __syncthreads();
  int wo = 0;
  #pragma unroll
  for (int w=0; w<8; ++w) wo += (w < wave) ? lds[w] : 0;
  return wo + x - v;
}

// reversed-prefix scan over hist[256] (first 256 threads active); picks
// descending-rank crossings r0 and (if do1) r1 into sOut {bin0,rem0,bin1,rem1}
__device__ void scan_pick(const int* hist, int r0, int r1, bool do1,
                          int* P, int* lds4, int* sOut, int tid, int lane){
  int Pt = 0;
  const int wave = tid >> 6;
  if (tid < 256){
    int x = hist[255 - tid];
    #pragma unroll
    for (int off=1; off<64; off<<=1){
      int y = __shfl_up(x, off, 64);
      if (lane >= off) x += y;
    }
    if (lane==63) lds4[wave] = x;
    Pt = x;
  }
  __syncthreads();
  if (tid < 256){
    int wo = 0;
    #pragma unroll
    for (int w=0; w<4; ++w) wo += (w < wave) ? lds4[w] : 0;
    Pt += wo;
    P[tid] = Pt;
  }
  __syncthreads();
  if (tid < 256){
    int prev = tid ? P[tid-1] : 0;
    if (Pt >= r0 && prev < r0){ sOut[0] = 255-tid; sOut[1] = r0-prev; }
    if (do1 && Pt >= r1 && prev < r1){ sOut[2] = 255-tid; sOut[3] = r1-prev; }
  }
  __syncthreads();
}

// one block (512 thr) per batch: dual-rank radix select from register keys
__global__ __launch_bounds__(512, 1)
void k_select(const unsigned* __restrict__ keys, const int* __restrict__ gpart,
              const int* __restrict__ seq, float* __restrict__ out, int K){
  const int b = blockIdx.x;
  const int tid = threadIdx.x;
  const int lane = tid & 63, wave = tid >> 6;
  __shared__ unsigned whA[8][257];      // per-wave private hists (257 pad rotates banks)
  __shared__ unsigned whB[8][257];
  __shared__ int histA[256];
  __shared__ int histB[256];
  __shared__ int P[256];
  __shared__ int part2[2][256];
  __shared__ int lds[8];
  __shared__ int lds4[4];
  __shared__ int smax[8];
  __shared__ int sOut[8];               // [0..3]=A pass, [4..7]=B pass
  __shared__ int sFill;

  int num_keep = seq[b]*2; if (num_keep < 1) num_keep = 1;   // num_keep <= K

  // ---- reduce 64 per-block partials into round-0 histogram (2-group) ----
  {
    int grp = tid >> 8;          // 0..1
    int bin = tid & 255;
    const int* gp = gpart + (b*64 + grp*32)*256 + bin;
    int sum = 0;
    #pragma unroll
    for (int w=0; w<32; ++w) sum += gp[w*256];
    part2[grp][bin] = sum;
  }

  // ---- load 32 consecutive keys per thread into registers (read once) ----
  const unsigned* kb = keys + (size_t)b*NN + tid*32;
  unsigned kk[32];
  #pragma unroll
  for (int q=0;q<8;++q){
    uint4 v = ((const uint4*)kb)[q];
    kk[4*q+0]=v.x; kk[4*q+1]=v.y; kk[4*q+2]=v.z; kk[4*q+3]=v.w;
  }
  __syncthreads();   // part2 ready

  // ---- round 0 from partials: both ranks share the same histogram ----
  int r0 = K, r1 = num_keep;
  if (tid < 256){
    int bin = tid;
    histA[bin] = part2[0][bin] + part2[1][bin];
  }
  __syncthreads();
  scan_pick(histA, r0, r1, true, P, lds4, sOut, tid, lane);
  unsigned pref0 = (unsigned)sOut[0] << 24;  r0 = sOut[1];
  unsigned pref1 = (unsigned)sOut[2] << 24;  r1 = sOut[3];
  bool same = (pref0 == pref1);
  unsigned decided = 0xFF000000u;
  __syncthreads();   // sOut consumed

  // ---- rounds 1..3: one key pass builds A (and B when diverged) ----
  for (int round=1; round<4; ++round){
    const int shift = 24 - 8*round;
    // clear wave-private hists
    #pragma unroll
    for (int i=0;i<4;++i){
      whA[wave][lane + 64*i] = 0u;
      whB[wave][lane + 64*i] = 0u;
    }
    __syncthreads();
    const bool dual = !same;
    #pragma unroll
    for (int j=0;j<32;++j){
      unsigned k = kk[j];
      if (((k ^ pref0) & decided) == 0u)
        atomicAdd(&whA[wave][(k>>shift)&255u], 1u);
      if (dual && ((k ^ pref1) & decided) == 0u)
        atomicAdd(&whB[wave][(k>>shift)&255u], 1u);
    }
    __syncthreads();
    if (tid < 256){
      unsigned sa_=0, sb_=0;
      #pragma unroll
      for (int w=0;w<8;++w){ sa_ += whA[w][tid]; sb_ += whB[w][tid]; }
      histA[tid] = (int)sa_;
      histB[tid] = (int)sb_;
    }
    __syncthreads();
    scan_pick(histA, r0, r1, same, P, lds4, sOut, tid, lane);
    if (dual)
      scan_pick(histB, r1, 0, false, P, lds4, sOut+4, tid, lane);
    int bin0 = sOut[0], rem0 = sOut[1];
    int bin1 = dual ? sOut[4] : sOut[2];
    int rem1 = dual ? sOut[5] : sOut[3];
    __syncthreads();   // sOut consumed before next round
    pref0 |= (unsigned)bin0 << shift;  r0 = rem0;
    pref1 |= (unsigned)bin1 << shift;  r1 = rem1;
    same = same && (bin0 == bin1);
    decided |= (0xFFu << shift);
  }
  const unsigned TK = pref0;  const int needK = r0;   // rank-K threshold (descending)
  const unsigned TN = pref1;  const int needN = r1;   // rank-num_keep threshold

  // ---- tie-rank offsets: one packed scan (no cross-field carry: sums<=16384) ----
  int cTK=0, cTN=0;
  #pragma unroll
  for (int j=0;j<32;++j){
    unsigned k = kk[j];
    cTK += (k==TK); cTN += (k==TN);
  }
  int packed = block_scan_excl512((cTK<<16)|cTN, lds, tid);
  int oTK = (packed>>16)&0xFFFF, oTN = packed&0xFFFF;

  const int base = tid*32;
  int tK=oTK, tN=oTN, cKept=0, maxIdx=-1;
  #pragma unroll
  for (int j=0;j<32;++j){
    unsigned k=kk[j];
    bool inK  = (k>TK) || ((k==TK) && (tK<needK));  if (k==TK) tK++;
    bool kept = (k>TN) || ((k==TN) && (tN<needN));  if (k==TN) tN++;
    if (inK) maxIdx = base+j;                 // ascending j -> last wins = max
    cKept += kept;
  }
  int oKept = block_scan_excl512(cKept, lds, tid);   // ascending-index output slot

  // fill = max index in the full top-K set
  int mv=maxIdx;
  #pragma unroll
  for (int off=32; off; off>>=1){
    int y = __shfl_down(mv, off, 64);
    mv = mv > y ? mv : y;
  }
  if (lane==0) smax[wave]=mv;
  __syncthreads();
  if (tid==0){
    int f=-1;
    #pragma unroll
    for (int i=0;i<8;++i) f = f > smax[i] ? f : smax[i];
    sFill = f;
  }
  __syncthreads();
  const int fill = sFill;

  // output layout: [idx BK][emb BKD][scores BK][mask BK], all float32
  float* out_idx = out;
  float* out_sc  = out + (size_t)NB*K + (size_t)NB*K*ND;
  float* out_mk  = out_sc + (size_t)NB*K;
  const int ob = b*K;
  const unsigned kNEG = fkey(NEG_FILL_F);

  int tN2=oTN, p=oKept;
  #pragma unroll
  for (int j=0;j<32;++j){
    unsigned k=kk[j];
    bool kept = (k>TN) || ((k==TN) && (tN2<needN));  if (k==TN) tN2++;
    if (kept){
      int n = base+j;
      out_idx[ob+p] = (float)n;
      out_sc[ob+p]  = fkey_inv(k);
      out_mk[ob+p]  = (k != kNEG) ? 1.0f : 0.0f;
      ++p;
    }
  }
  if (num_keep < K){
    float fs = fkey_inv(keys[(size_t)b*NN + fill]);
    for (int q = num_keep + tid; q < K; q += 512){
      out_idx[ob+q] = (float)fill;
      out_sc[ob+q]  = fs;
      out_mk[ob+q]  = 0.0f;
    }
  }
}

// out_emb[b,p,:] = embeddings[b, idx[b,p], :]; grid.y = batch, no division
__global__ void k_gather(const float* __restrict__ emb, const float* __restrict__ out_idx,
                         float* __restrict__ out_emb, int K){
  int b = blockIdx.y;
  int g = blockIdx.x*256 + threadIdx.x;   // float4 slot within batch: K*64 slots
  if (g >= K*64) return;
  int c = g & 63;                          // float4 column 0..63
  int p = g >> 6;                          // row within batch
  size_t r = (size_t)b*K + p;
  int idx = (int)out_idx[r];
  const float4* src = (const float4*)(emb + ((size_t)b*NN + (size_t)idx)*ND);
  float4* dst = (float4*)(out_emb + r*(size_t)ND);
  dst[c] = src[c];
}

extern "C" void kernel_launch(void* const* d_in, const int* in_sizes, int n_in,
                              void* d_out, int out_size, void* d_ws, size_t ws_size,
                              hipStream_t stream) {
  const float* emb  = (const float*)d_in[0];
  const float* sa   = (const float*)d_in[1];
  const float* sb   = (const float*)d_in[2];
  const int*   mask = (const int*)d_in[3];
  const int*   seq  = (const int*)d_in[4];
  float* out = (float*)d_out;
  unsigned* ws_keys = (unsigned*)d_ws;            // B*N uints = 512 KB
  int* gpart = (int*)d_ws + (size_t)NB*NN;        // 512 blocks * 256 bins

  int K = out_size / (NB*(ND+3));    // out_size = B*K*(D+3)
  if (K <= 0) return;

  k_scores<<<(NB*NN)/256, 256, 0, stream>>>(sa, sb, mask, ws_keys, gpart);
  k_select<<<NB, 512, 0, stream>>>(ws_keys, gpart, seq, out, K);
  dim3 ggrid((K*64 + 255)/256, NB);
  k_gather<<<ggrid, 256, 0, stream>>>(emb, out, out + (size_t)NB*K, K);
}

// Round 6
// 206.038 us; speedup vs baseline: 1.0208x; 1.0208x over previous
//
#include <hip/hip_runtime.h>
#include <math.h>

#define NB 8
#define NN 16384
#define NT 8
#define ND 256
#define NEG_FILL_F (-1e20f)

// monotonic float->uint key: order(key) == order(float), ascending
__device__ __forceinline__ unsigned fkey(float s){
  unsigned u = __float_as_uint(s);
  return (u & 0x80000000u) ? ~u : (u | 0x80000000u);
}
__device__ __forceinline__ float fkey_inv(unsigned k){
  unsigned u = (k & 0x80000000u) ? (k ^ 0x80000000u) : ~k;
  return __uint_as_float(u);
}

__device__ __forceinline__ float prob_of(const float4 x, const float4 y){
  float m = fmaxf(fmaxf(fmaxf(x.x,x.y),fmaxf(x.z,x.w)),
                  fmaxf(fmaxf(y.x,y.y),fmaxf(y.z,y.w)));
  float e0=expf(x.x-m), e1=expf(x.y-m), e2=expf(x.z-m), e3=expf(x.w-m);
  float e4=expf(y.x-m), e5=expf(y.y-m), e6=expf(y.z-m), e7=expf(y.w-m);
  float sum = ((((((e0+e1)+e2)+e3)+e4)+e5)+e6)+e7;
  float pm = fmaxf(fmaxf(fmaxf(e1,e2),fmaxf(e3,e4)),fmaxf(fmaxf(e5,e6),e7));
  return pm/sum;   // max_{t>=1} softmax[t] == max_{t>=1} e_t / sum (division monotone)
}

// keys[b,n] = fkey( span_mask ? max(prob_a, prob_b) : NEG_FILL )
// writes this block's high-byte histogram to its private gpart slot (no atomics, no init)
__global__ void k_scores(const float* __restrict__ sa, const float* __restrict__ sb,
                         const int* __restrict__ mask, unsigned* __restrict__ outk,
                         int* __restrict__ gpart){
  __shared__ int lh[256];
  const int t = threadIdx.x;
  lh[t] = 0;
  __syncthreads();
  int i = blockIdx.x*256 + t;            // 256 threads/block, 64 blocks per batch
  const float4* pa = (const float4*)(sa + (size_t)i*NT);
  const float4* pb = (const float4*)(sb + (size_t)i*NT);
  float4 a0=pa[0], a1=pa[1], b0=pb[0], b1=pb[1];
  float p = fmaxf(prob_of(a0,a1), prob_of(b0,b1));
  unsigned k = fkey(mask[i] ? p : NEG_FILL_F);
  outk[i] = k;
  atomicAdd(&lh[k>>24], 1);
  __syncthreads();
  gpart[blockIdx.x*256 + t] = lh[t];     // full 256-bin partial, plain store
}

// exclusive scan over 1024 threads (thread order == span order)
__device__ int block_scan_excl(int v, int* lds, int tid){
  __syncthreads();   // protect lds reuse across calls
  int lane = tid & 63, wave = tid >> 6;
  int x = v;
  #pragma unroll
  for (int off=1; off<64; off<<=1){
    int y = __shfl_up(x, off, 64);
    if (lane >= off) x += y;
  }
  if (lane == 63) lds[wave] = x;       // wave totals
  __syncthreads();
  if (wave == 0){
    int w = (lane < 16) ? lds[lane] : 0;
    #pragma unroll
    for (int off=1; off<16; off<<=1){
      int y = __shfl_up(w, off, 64);
      if (lane >= off) w += y;
    }
    if (lane < 16) lds[16+lane] = w;   // inclusive scan of wave totals
  }
  __syncthreads();
  int waveOff = wave ? lds[16+wave-1] : 0;
  return waveOff + x - v;
}

// reversed-prefix scan of x (=hist[255-tid] for tid<256); picks descending-rank
// crossings for r0 and (if do1) r1. sOut = {bin0, rem0, bin1, rem1}
__device__ void scan_pick2(int x, int r0, int r1, bool do1,
                           int* P, int* lds4, int* sOut, int tid, int lane, int wave){
  int Pt = 0;
  if (tid < 256){
    #pragma unroll
    for (int off=1; off<64; off<<=1){
      int y = __shfl_up(x, off, 64);
      if (lane >= off) x += y;
    }
    if (lane==63) lds4[wave] = x;
    Pt = x;
  }
  __syncthreads();
  if (tid < 256){
    int offs = 0;
    for (int w=0; w<wave; ++w) offs += lds4[w];
    Pt += offs;
    P[tid] = Pt;
  }
  __syncthreads();
  if (tid < 256){
    int prev = tid ? P[tid-1] : 0;
    if (Pt >= r0 && prev < r0){ sOut[0] = 255-tid; sOut[1] = r0-prev; }
    if (do1 && Pt >= r1 && prev < r1){ sOut[2] = 255-tid; sOut[3] = r1-prev; }
  }
  __syncthreads();
}

// one block per batch: dual-rank radix select from register-cached keys,
// prefix-scan placement, writes top_indices / top_scores / top_mask
__global__ __launch_bounds__(1024)
void k_select(const unsigned* __restrict__ keys, const int* __restrict__ gpart,
              const int* __restrict__ seq, float* __restrict__ out, int K){
  const int b = blockIdx.x;
  const int tid = threadIdx.x;
  const int lane = tid & 63, wave = tid >> 6;
  __shared__ unsigned whA[16][257];   // per-wave private hists; pad 257 rotates banks
  __shared__ unsigned whB[16][257];
  __shared__ int part4[4][256];
  __shared__ int histA[256];
  __shared__ int histB[256];
  __shared__ int P[256];
  __shared__ int lds[32];
  __shared__ int lds4[4];
  __shared__ int smax[16];
  __shared__ int sOut[8];               // [0..3]=A pass, [4..7]=B pass
  __shared__ int sFill;

  int num_keep = seq[b]*2; if (num_keep < 1) num_keep = 1;   // num_keep <= K by construction

  // ---- reduce 64 per-block partials into round-0 histogram (4-way parallel) ----
  {
    int grp = tid >> 8;          // 0..3
    int bin = tid & 255;
    const int* gp = gpart + (b*64 + grp*16)*256 + bin;
    int sum = 0;
    #pragma unroll
    for (int w=0; w<16; ++w) sum += gp[w*256];
    part4[grp][bin] = sum;
  }

  // ---- load 16 consecutive keys per thread into registers (read once) ----
  const unsigned* kb = keys + (size_t)b*NN + tid*16;
  unsigned kk[16];
  #pragma unroll
  for (int q=0;q<4;++q){
    uint4 v = ((const uint4*)kb)[q];
    kk[4*q+0]=v.x; kk[4*q+1]=v.y; kk[4*q+2]=v.z; kk[4*q+3]=v.w;
  }
  __syncthreads();   // part4 ready

  // ---- round 0 from partials: both ranks share the same histogram ----
  int r0 = K, r1 = num_keep;
  int x0 = 0;
  if (tid < 256){
    int bin = 255 - tid;
    x0 = part4[0][bin] + part4[1][bin] + part4[2][bin] + part4[3][bin];
  }
  scan_pick2(x0, r0, r1, true, P, lds4, sOut, tid, lane, wave);
  unsigned pref0 = (unsigned)sOut[0] << 24;  r0 = sOut[1];
  unsigned pref1 = (unsigned)sOut[2] << 24;  r1 = sOut[3];
  bool same = (pref0 == pref1);
  unsigned decided = 0xFF000000u;
  __syncthreads();   // sOut consumed

  // ---- rounds 1..3: ONE key pass builds A (and B when diverged) ----
  for (int round=1; round<4; ++round){
    const int shift = 24 - 8*round;
    #pragma unroll
    for (int i=0;i<4;++i){
      whA[wave][lane + 64*i] = 0u;
      whB[wave][lane + 64*i] = 0u;
    }
    __syncthreads();
    const bool dual = !same;
    #pragma unroll
    for (int j=0;j<16;++j){
      unsigned k = kk[j];
      if (((k ^ pref0) & decided) == 0u)
        atomicAdd(&whA[wave][(k>>shift)&255u], 1u);
      if (dual && ((k ^ pref1) & decided) == 0u)
        atomicAdd(&whB[wave][(k>>shift)&255u], 1u);
    }
    __syncthreads();
    if (tid < 256){
      unsigned sa_=0, sb_=0;
      #pragma unroll
      for (int w=0;w<16;++w){ sa_ += whA[w][tid]; sb_ += whB[w][tid]; }
      histA[tid] = (int)sa_;
      histB[tid] = (int)sb_;
    }
    __syncthreads();
    int xa = (tid < 256) ? histA[255-tid] : 0;
    scan_pick2(xa, r0, r1, same, P, lds4, sOut, tid, lane, wave);
    if (dual){
      int xb = (tid < 256) ? histB[255-tid] : 0;
      scan_pick2(xb, r1, 0, false, P, lds4, sOut+4, tid, lane, wave);
    }
    int bin0 = sOut[0], rem0 = sOut[1];
    int bin1 = dual ? sOut[4] : sOut[2];
    int rem1 = dual ? sOut[5] : sOut[3];
    __syncthreads();   // sOut consumed before next round
    pref0 |= (unsigned)bin0 << shift;  r0 = rem0;
    pref1 |= (unsigned)bin1 << shift;  r1 = rem1;
    same = same && (bin0 == bin1);
    decided |= (0xFFu << shift);
  }
  const unsigned TK = pref0;  const int needK = r0;   // rank-K threshold (descending)
  const unsigned TN = pref1;  const int needN = r1;   // rank-num_keep threshold

  // ---- tie-rank offsets: one packed scan (fields sum <=16384, no carry) ----
  int cTK=0, cTN=0;
  #pragma unroll
  for (int j=0;j<16;++j){
    unsigned k = kk[j];
    cTK += (k==TK); cTN += (k==TN);
  }
  int packed = block_scan_excl((cTK<<16)|cTN, lds, tid);
  int oTK = (packed>>16)&0xFFFF, oTN = packed&0xFFFF;

  const int base = tid*16;
  int tK=oTK, tN=oTN, cKept=0, maxIdx=-1;
  #pragma unroll
  for (int j=0;j<16;++j){
    unsigned k=kk[j];
    bool inK  = (k>TK) || ((k==TK) && (tK<needK));  if (k==TK) tK++;
    bool kept = (k>TN) || ((k==TN) && (tN<needN));  if (k==TN) tN++;
    if (inK) maxIdx = base+j;                 // ascending j -> last wins = max
    cKept += kept;
  }
  int oKept = block_scan_excl(cKept, lds, tid);   // ascending-index output slot

  // fill = max index in the full top-K set
  int mv=maxIdx;
  #pragma unroll
  for (int off=32; off; off>>=1){
    int y = __shfl_down(mv, off, 64);
    mv = mv > y ? mv : y;
  }
  if (lane==0) smax[wave]=mv;
  __syncthreads();
  if (tid==0){
    int f=-1;
    #pragma unroll
    for (int i=0;i<16;++i) f = f > smax[i] ? f : smax[i];
    sFill = f;
  }
  __syncthreads();
  const int fill = sFill;

  // output layout: [idx BK][emb BKD][scores BK][mask BK], all float32
  float* out_idx = out;
  float* out_sc  = out + (size_t)NB*K + (size_t)NB*K*ND;
  float* out_mk  = out_sc + (size_t)NB*K;
  const int ob = b*K;
  const unsigned kNEG = fkey(NEG_FILL_F);

  int tN2=oTN, p=oKept;
  #pragma unroll
  for (int j=0;j<16;++j){
    unsigned k=kk[j];
    bool kept = (k>TN) || ((k==TN) && (tN2<needN));  if (k==TN) tN2++;
    if (kept){
      int n = base+j;
      out_idx[ob+p] = (float)n;
      out_sc[ob+p]  = fkey_inv(k);
      out_mk[ob+p]  = (k != kNEG) ? 1.0f : 0.0f;
      ++p;
    }
  }
  if (num_keep < K){
    float fs = fkey_inv(keys[(size_t)b*NN + fill]);
    for (int q = num_keep + tid; q < K; q += 1024){
      out_idx[ob+q] = (float)fill;
      out_sc[ob+q]  = fs;
      out_mk[ob+q]  = 0.0f;
    }
  }
}

// out_emb[b,p,:] = embeddings[b, idx[b,p], :]; grid.y = batch, no division
__global__ void k_gather(const float* __restrict__ emb, const float* __restrict__ out_idx,
                         float* __restrict__ out_emb, int K){
  int b = blockIdx.y;
  int g = blockIdx.x*256 + threadIdx.x;   // float4 slot within batch: K*64 slots
  if (g >= K*64) return;
  int c = g & 63;                          // float4 column 0..63
  int p = g >> 6;                          // row within batch
  size_t r = (size_t)b*K + p;
  int idx = (int)out_idx[r];
  const float4* src = (const float4*)(emb + ((size_t)b*NN + (size_t)idx)*ND);
  float4* dst = (float4*)(out_emb + r*(size_t)ND);
  dst[c] = src[c];
}

extern "C" void kernel_launch(void* const* d_in, const int* in_sizes, int n_in,
                              void* d_out, int out_size, void* d_ws, size_t ws_size,
                              hipStream_t stream) {
  const float* emb  = (const float*)d_in[0];
  const float* sa   = (const float*)d_in[1];
  const float* sb   = (const float*)d_in[2];
  const int*   mask = (const int*)d_in[3];
  const int*   seq  = (const int*)d_in[4];
  float* out = (float*)d_out;
  unsigned* ws_keys = (unsigned*)d_ws;            // B*N uints = 512 KB
  int* gpart = (int*)d_ws + (size_t)NB*NN;        // 512 blocks * 256 bins

  int K = out_size / (NB*(ND+3));    // out_size = B*K*(D+3)
  if (K <= 0) return;

  k_scores<<<(NB*NN)/256, 256, 0, stream>>>(sa, sb, mask, ws_keys, gpart);
  k_select<<<NB, 1024, 0, stream>>>(ws_keys, gpart, seq, out, K);
  dim3 ggrid((K*64 + 255)/256, NB);
  k_gather<<<ggrid, 256, 0, stream>>>(emb, out, out + (size_t)NB*K, K);
}